// Round 3
// baseline (921.330 us; speedup 1.0000x reference)
//
#include <hip/hip_runtime.h>
#include <math.h>

#define B_ 16
#define M_ 1024
#define N_ 1024
#define D_ 512
#define MP1 1025
#define NP1 1025
#define NUM_SINK 8
#define BK 64
#define SH_STRIDE 1032   // fp16 row stride (elements), 16B-aligned rows
// log(1/2048), log(1/2)
#define LOG_NORM (-7.6246189861593985f)
#define LOG_HALF (-0.6931471805599453f)

typedef __attribute__((ext_vector_type(8))) short bf16x8;
typedef __attribute__((ext_vector_type(4))) float f32x4;
typedef __attribute__((ext_vector_type(8))) _Float16 h16x8;
typedef __attribute__((ext_vector_type(4))) _Float16 h16x4;

__device__ inline short f2bf(float x) {
    unsigned u = __builtin_bit_cast(unsigned, x);
    u = (u + 0x7FFFu + ((u >> 16) & 1u)) >> 16;
    return (short)u;
}

// ---------------- norms: one wave per feature row ----------------
__global__ __launch_bounds__(256) void norms_kernel(
    const float* __restrict__ tf, const float* __restrict__ df,
    float* __restrict__ inv1, float* __restrict__ inv2)
{
    int w = (blockIdx.x * 256 + threadIdx.x) >> 6;
    int lane = threadIdx.x & 63;
    if (w >= B_ * 2048) return;
    int b = w >> 11;
    int rr = w & 2047;
    const float* src;
    float* dst;
    if (rr < M_) { src = tf + ((size_t)b * M_ + rr) * D_;        dst = inv1 + b * M_ + rr; }
    else         { src = df + ((size_t)b * N_ + (rr - M_)) * D_; dst = inv2 + b * N_ + (rr - M_); }
    float4 x = *(const float4*)(src + lane * 4);
    float4 y = *(const float4*)(src + 256 + lane * 4);
    float ss = x.x*x.x + x.y*x.y + x.z*x.z + x.w*x.w
             + y.x*y.x + y.y*y.y + y.z*y.z + y.w*y.w;
    #pragma unroll
    for (int o = 32; o; o >>= 1) ss += __shfl_xor(ss, o);
    if (lane == 0) *dst = 1.0f / sqrtf(ss);
}

// ---------------- MFMA GEMM + epilogue: S = (cos*mask - 1)/lambda ----------------
// 128x128 tile, BK=64, 4 waves (2x2), 4x4 frags of 16x16x32 bf16. 1-D grid + XCD swizzle.
template<bool HALF>
__global__ __launch_bounds__(256) void gemm_s_kernel(
    const float* __restrict__ A, const float* __restrict__ Bm,
    const float* __restrict__ tl, const float* __restrict__ dl,
    const float* __restrict__ inv1, const float* __restrict__ inv2,
    const float* __restrict__ eps_p, void* __restrict__ Sout)
{
    __shared__ __align__(16) unsigned short As[128 * BK];
    __shared__ __align__(16) unsigned short Bs[128 * BK];

    // bijective XCD swizzle: 1024 blocks, 8 XCDs -> each XCD gets 2 contiguous batches
    int flat = blockIdx.x;
    int swz = (flat & 7) * 128 + (flat >> 3);
    int jb = swz & 7, ib = (swz >> 3) & 7;
    int b  = swz >> 6;
    int i0 = ib * 128;
    int j0 = jb * 128;

    const float* Ab = A  + (size_t)b * M_ * D_;
    const float* Bb = Bm + (size_t)b * N_ * D_;

    int tid  = threadIdx.x;
    int lane = tid & 63;
    int w    = tid >> 6;
    int wm   = w >> 1, wn = w & 1;

    int seg   = tid & 7;
    int rbase = tid >> 3;

    f32x4 acc[4][4] = {};

    for (int k0 = 0; k0 < D_; k0 += BK) {
        #pragma unroll
        for (int rr = 0; rr < 4; ++rr) {
            int r = rbase + rr * 32;
            int colx = (seg * 16) ^ ((r & 7) << 4);
            {
                const float* pa = Ab + (size_t)(i0 + r) * D_ + k0 + seg * 8;
                float4 a0 = *(const float4*)pa;
                float4 a1 = *(const float4*)(pa + 4);
                bf16x8 hv;
                hv[0] = f2bf(a0.x); hv[1] = f2bf(a0.y); hv[2] = f2bf(a0.z); hv[3] = f2bf(a0.w);
                hv[4] = f2bf(a1.x); hv[5] = f2bf(a1.y); hv[6] = f2bf(a1.z); hv[7] = f2bf(a1.w);
                *(bf16x8*)((char*)As + r * 128 + colx) = hv;
            }
            {
                const float* pb = Bb + (size_t)(j0 + r) * D_ + k0 + seg * 8;
                float4 b0 = *(const float4*)pb;
                float4 b1 = *(const float4*)(pb + 4);
                bf16x8 hv;
                hv[0] = f2bf(b0.x); hv[1] = f2bf(b0.y); hv[2] = f2bf(b0.z); hv[3] = f2bf(b0.w);
                hv[4] = f2bf(b1.x); hv[5] = f2bf(b1.y); hv[6] = f2bf(b1.z); hv[7] = f2bf(b1.w);
                *(bf16x8*)((char*)Bs + r * 128 + colx) = hv;
            }
        }
        __syncthreads();

        #pragma unroll
        for (int ks = 0; ks < 2; ++ks) {
            int kb = ks * 64 + ((lane >> 4) << 4);
            bf16x8 af[4], bfr[4];
            #pragma unroll
            for (int m = 0; m < 4; ++m) {
                int ra = wm * 64 + m * 16 + (lane & 15);
                af[m] = *(const bf16x8*)((const char*)As + ra * 128 + (kb ^ ((ra & 7) << 4)));
                int rb = wn * 64 + m * 16 + (lane & 15);
                bfr[m] = *(const bf16x8*)((const char*)Bs + rb * 128 + (kb ^ ((rb & 7) << 4)));
            }
            #pragma unroll
            for (int m = 0; m < 4; ++m)
                #pragma unroll
                for (int n = 0; n < 4; ++n)
                    acc[m][n] = __builtin_amdgcn_mfma_f32_16x16x32_bf16(af[m], bfr[n], acc[m][n], 0, 0, 0);
        }
        __syncthreads();
    }

    float lam = expf(eps_p[0]) + 0.03f;
    float inv_lam = 1.0f / lam;
    int crow0 = i0 + wm * 64;
    int ccol0 = j0 + wn * 64;
    int rlane = lane >> 4;
    int clane = lane & 15;

    float invb_[4], dlx_[4], dly_[4];
    #pragma unroll
    for (int n = 0; n < 4; ++n) {
        int j = ccol0 + n * 16 + clane;
        invb_[n] = inv2[b * N_ + j];
        dlx_[n]  = dl[((size_t)b * N_ + j) * 2 + 0];
        dly_[n]  = dl[((size_t)b * N_ + j) * 2 + 1];
    }
    #pragma unroll
    for (int m = 0; m < 4; ++m) {
        #pragma unroll
        for (int reg = 0; reg < 4; ++reg) {
            int i = crow0 + m * 16 + rlane * 4 + reg;
            float inva = inv1[b * M_ + i];
            float tlx  = tl[((size_t)b * M_ + i) * 2 + 0];
            float tly  = tl[((size_t)b * M_ + i) * 2 + 1];
            #pragma unroll
            for (int n = 0; n < 4; ++n) {
                float cosv = acc[m][n][reg] * inva * invb_[n];
                float dx = tlx - dlx_[n];
                float dy = tly - dly_[n];
                float msk = (sqrtf(dx * dx + dy * dy) <= 0.3f) ? 1.0f : 0.0f;
                float val = (cosv * msk - 1.0f) * inv_lam;
                int col = ccol0 + n * 16 + clane;
                if (HALF) {
                    _Float16* Srow = (_Float16*)Sout + ((size_t)b * MP1 + i) * SH_STRIDE;
                    Srow[col] = (_Float16)val;
                } else {
                    float* Srow = (float*)Sout + ((size_t)b * MP1 + i) * NP1;
                    Srow[col] = val;
                }
            }
        }
    }
}

// ---------------- fill dustbin row/col ----------------
template<bool HALF>
__global__ __launch_bounds__(256) void fill_edges_kernel(
    void* __restrict__ Sout, const float* __restrict__ alpha_p, const float* __restrict__ eps_p)
{
    int t = blockIdx.x * 256 + threadIdx.x;
    if (t >= B_ * (NP1 + M_)) return;
    int b = t / (NP1 + M_), r = t % (NP1 + M_);
    float lam = expf(eps_p[0]) + 0.03f;
    float s = (alpha_p[0] - 1.0f) / lam;
    size_t stride = HALF ? SH_STRIDE : NP1;
    size_t idx;
    if (r < NP1) idx = ((size_t)b * MP1 + M_) * stride + r;
    else         idx = ((size_t)b * MP1 + (r - NP1)) * stride + N_;
    if (HALF) ((_Float16*)Sout)[idx] = (_Float16)s;
    else      ((float*)Sout)[idx] = s;
}

// ================= fp16 path kernels =================

__global__ __launch_bounds__(256) void row_pass_h(
    const _Float16* __restrict__ Sh, const float* __restrict__ v, float* __restrict__ u)
{
    int w = (blockIdx.x * 256 + threadIdx.x) >> 6;
    int lane = threadIdx.x & 63;
    if (w >= B_ * MP1) return;
    int b = w / MP1, i = w % MP1;
    const _Float16* row = Sh + ((size_t)b * MP1 + i) * SH_STRIDE;
    const float* vb = v + b * NP1;
    h16x8 h0 = *(const h16x8*)(row + lane * 16);
    h16x8 h1 = *(const h16x8*)(row + lane * 16 + 8);
    float t[17];
    float mx = -INFINITY;
    #pragma unroll
    for (int e = 0; e < 8; ++e) {
        t[e]     = (float)h0[e] + vb[lane * 16 + e];
        t[e + 8] = (float)h1[e] + vb[lane * 16 + 8 + e];
    }
    t[16] = (lane == 0) ? ((float)row[1024] + vb[1024]) : -INFINITY;
    #pragma unroll
    for (int e = 0; e < 17; ++e) mx = fmaxf(mx, t[e]);
    #pragma unroll
    for (int o = 32; o; o >>= 1) mx = fmaxf(mx, __shfl_xor(mx, o));
    float sm = 0.f;
    #pragma unroll
    for (int e = 0; e < 17; ++e) sm += expf(t[e] - mx);
    #pragma unroll
    for (int o = 32; o; o >>= 1) sm += __shfl_xor(sm, o);
    if (lane == 0) {
        float la = (i == M_) ? LOG_HALF : LOG_NORM;
        u[b * MP1 + i] = la - (mx + logf(sm));
    }
}

__global__ __launch_bounds__(256) void col_pass1_h(
    const _Float16* __restrict__ Sh, const float* __restrict__ u,
    float* __restrict__ pm, float* __restrict__ ps)
{
    int jt = blockIdx.x * 256 + threadIdx.x;
    int j0 = jt * 4;
    if (j0 >= NP1) return;
    int b = blockIdx.z;
    int i0 = blockIdx.y * 128;
    int i1 = min(i0 + 128, MP1);
    const _Float16* p = Sh + ((size_t)b * MP1 + i0) * SH_STRIDE + j0;
    const float* ub = u + b * MP1;
    float m[4] = {-INFINITY, -INFINITY, -INFINITY, -INFINITY};
    float sm[4] = {};
    for (int i = i0; i < i1; ++i) {
        h16x4 hv = *(const h16x4*)p;
        float ui = ub[i];
        #pragma unroll
        for (int c = 0; c < 4; ++c) {
            float val = (float)hv[c] + ui;
            float nm = fmaxf(m[c], val);
            sm[c] = sm[c] * expf(m[c] - nm) + expf(val - nm);
            m[c] = nm;
        }
        p += SH_STRIDE;
    }
    #pragma unroll
    for (int c = 0; c < 4; ++c) {
        int j = j0 + c;
        if (j < NP1) {
            int idx = (blockIdx.y * B_ + b) * NP1 + j;
            pm[idx] = m[c];
            ps[idx] = sm[c];
        }
    }
}

__global__ __launch_bounds__(256) void col_pass2_kernel(
    const float* __restrict__ pm, const float* __restrict__ ps, float* __restrict__ v)
{
    int j = blockIdx.x * 256 + threadIdx.x;
    int b = blockIdx.y;
    if (j >= NP1) return;
    float M = -INFINITY;
    #pragma unroll
    for (int c = 0; c < 9; ++c) M = fmaxf(M, pm[(c * B_ + b) * NP1 + j]);
    float Ssum = 0.f;
    #pragma unroll
    for (int c = 0; c < 9; ++c) Ssum += ps[(c * B_ + b) * NP1 + j] * expf(pm[(c * B_ + b) * NP1 + j] - M);
    float lb = (j == N_) ? LOG_HALF : LOG_NORM;
    v[b * NP1 + j] = lb - (M + logf(Ssum));
}

// fused final row pass + finalize: reads fp16 S, writes fp32 out (coalesced)
__global__ __launch_bounds__(256) void row_final_h(
    const _Float16* __restrict__ Sh, const float* __restrict__ v, float* __restrict__ out)
{
    int w = (blockIdx.x * 256 + threadIdx.x) >> 6;
    int lane = threadIdx.x & 63;
    if (w >= B_ * MP1) return;
    int b = w / MP1, i = w % MP1;
    const _Float16* row = Sh + ((size_t)b * MP1 + i) * SH_STRIDE;
    float* orow = out + ((size_t)b * MP1 + i) * NP1;
    const float* vb = v + b * NP1;
    float t[17];
    float mx = -INFINITY;
    #pragma unroll
    for (int q = 0; q < 17; ++q) {
        int j = lane + q * 64;
        float val = -INFINITY;
        if (j < NP1) val = (float)row[j] + vb[j];
        t[q] = val;
        mx = fmaxf(mx, val);
    }
    #pragma unroll
    for (int o = 32; o; o >>= 1) mx = fmaxf(mx, __shfl_xor(mx, o));
    float sm = 0.f;
    #pragma unroll
    for (int q = 0; q < 17; ++q) sm += expf(t[q] - mx);
    #pragma unroll
    for (int o = 32; o; o >>= 1) sm += __shfl_xor(sm, o);
    float la = (i == M_) ? LOG_HALF : LOG_NORM;
    float scale = la - (mx + logf(sm));
    #pragma unroll
    for (int q = 0; q < 17; ++q) {
        int j = lane + q * 64;
        if (j < NP1) orow[j] = expf(t[q] + scale) * 2048.0f;
    }
}

// ================= fp32 fallback kernels (S in d_out) =================

__global__ __launch_bounds__(256) void row_pass_kernel(
    const float* __restrict__ S, const float* __restrict__ v, float* __restrict__ u)
{
    int w = (blockIdx.x * 256 + threadIdx.x) >> 6;
    int lane = threadIdx.x & 63;
    if (w >= B_ * MP1) return;
    int b = w / MP1, i = w % MP1;
    const float* row = S + ((size_t)b * MP1 + i) * NP1;
    const float* vb = v + b * NP1;
    float t[17];
    float mx = -INFINITY;
    #pragma unroll
    for (int q = 0; q < 17; ++q) {
        int j = lane + q * 64;
        float val = -INFINITY;
        if (j < NP1) val = row[j] + vb[j];
        t[q] = val;
        mx = fmaxf(mx, val);
    }
    #pragma unroll
    for (int o = 32; o; o >>= 1) mx = fmaxf(mx, __shfl_xor(mx, o));
    float sm = 0.f;
    #pragma unroll
    for (int q = 0; q < 17; ++q) sm += expf(t[q] - mx);
    #pragma unroll
    for (int o = 32; o; o >>= 1) sm += __shfl_xor(sm, o);
    if (lane == 0) {
        float la = (i == M_) ? LOG_HALF : LOG_NORM;
        u[b * MP1 + i] = la - (mx + logf(sm));
    }
}

__global__ __launch_bounds__(256) void col_pass1_kernel(
    const float* __restrict__ S, const float* __restrict__ u,
    float* __restrict__ pm, float* __restrict__ ps)
{
    int j = blockIdx.x * 256 + threadIdx.x;
    int b = blockIdx.z;
    int i0 = blockIdx.y * 128;
    int i1 = min(i0 + 128, MP1);
    if (j >= NP1) return;
    const float* p  = S + ((size_t)b * MP1 + i0) * NP1 + j;
    const float* ub = u + b * MP1;
    float m = -INFINITY, sm = 0.f;
    for (int i = i0; i < i1; ++i) {
        float val = *p + ub[i];
        float nm = fmaxf(m, val);
        sm = sm * expf(m - nm) + expf(val - nm);
        m = nm;
        p += NP1;
    }
    int idx = (blockIdx.y * B_ + b) * NP1 + j;
    pm[idx] = m;
    ps[idx] = sm;
}

__global__ __launch_bounds__(256) void row_final_kernel(
    float* __restrict__ S, const float* __restrict__ v)
{
    int w = (blockIdx.x * 256 + threadIdx.x) >> 6;
    int lane = threadIdx.x & 63;
    if (w >= B_ * MP1) return;
    int b = w / MP1, i = w % MP1;
    float* row = S + ((size_t)b * MP1 + i) * NP1;
    const float* vb = v + b * NP1;
    float t[17];
    float mx = -INFINITY;
    #pragma unroll
    for (int q = 0; q < 17; ++q) {
        int j = lane + q * 64;
        float val = -INFINITY;
        if (j < NP1) val = row[j] + vb[j];
        t[q] = val;
        mx = fmaxf(mx, val);
    }
    #pragma unroll
    for (int o = 32; o; o >>= 1) mx = fmaxf(mx, __shfl_xor(mx, o));
    float sm = 0.f;
    #pragma unroll
    for (int q = 0; q < 17; ++q) sm += expf(t[q] - mx);
    #pragma unroll
    for (int o = 32; o; o >>= 1) sm += __shfl_xor(sm, o);
    float la = (i == M_) ? LOG_HALF : LOG_NORM;
    float scale = la - (mx + logf(sm));
    #pragma unroll
    for (int q = 0; q < 17; ++q) {
        int j = lane + q * 64;
        if (j < NP1) row[j] = expf(t[q] + scale) * 2048.0f;
    }
}

// ---------------- zero helper ----------------
__global__ __launch_bounds__(256) void zero_kernel(float* __restrict__ p, int n)
{
    int i = blockIdx.x * 256 + threadIdx.x;
    if (i < n) p[i] = 0.f;
}

extern "C" void kernel_launch(void* const* d_in, const int* in_sizes, int n_in,
                              void* d_out, int out_size, void* d_ws, size_t ws_size,
                              hipStream_t stream)
{
    const float* tf    = (const float*)d_in[0];
    const float* df    = (const float*)d_in[1];
    const float* tl    = (const float*)d_in[2];
    const float* dl    = (const float*)d_in[3];
    const float* alpha = (const float*)d_in[4];
    const float* eps   = (const float*)d_in[5];
    float* out = (float*)d_out;

    const size_t sh_elems = (size_t)B_ * MP1 * SH_STRIDE;           // fp16 elements
    const size_t sh_bytes = sh_elems * sizeof(_Float16);            // ~33.85 MB
    const size_t small_floats = (size_t)B_ * M_ * 2 + (size_t)B_ * MP1 * 2 + 2 * 9 * (size_t)B_ * NP1;
    const bool use_half = ws_size >= sh_bytes + small_floats * 4 + 256;

    int rowblocks = (B_ * MP1 + 3) / 4;

    if (use_half) {
        _Float16* Sh = (_Float16*)d_ws;
        float* fbase = (float*)((char*)d_ws + ((sh_bytes + 255) & ~(size_t)255));
        float* inv1 = fbase;
        float* inv2 = inv1 + B_ * M_;
        float* u    = inv2 + B_ * N_;
        float* v    = u + B_ * MP1;
        float* pm   = v + B_ * NP1;
        float* ps   = pm + 9 * B_ * NP1;

        zero_kernel<<<(B_ * NP1 + 255) / 256, 256, 0, stream>>>(v, B_ * NP1);
        norms_kernel<<<(B_ * 2048) / 4, 256, 0, stream>>>(tf, df, inv1, inv2);
        gemm_s_kernel<true><<<1024, 256, 0, stream>>>(tf, df, tl, dl, inv1, inv2, eps, Sh);
        fill_edges_kernel<true><<<(B_ * (NP1 + M_) + 255) / 256, 256, 0, stream>>>(Sh, alpha, eps);

        for (int it = 0; it < NUM_SINK; ++it) {
            row_pass_h<<<rowblocks, 256, 0, stream>>>(Sh, v, u);
            col_pass1_h<<<dim3(2, 9, 16), 256, 0, stream>>>(Sh, u, pm, ps);
            col_pass2_kernel<<<dim3(5, 16), 256, 0, stream>>>(pm, ps, v);
        }
        row_final_h<<<rowblocks, 256, 0, stream>>>(Sh, v, out);
    } else {
        float* S = out;
        float* ws = (float*)d_ws;
        float* inv1 = ws;
        float* inv2 = inv1 + B_ * M_;
        float* u    = inv2 + B_ * N_;
        float* v    = u + B_ * MP1;
        float* pm   = v + B_ * NP1;
        float* ps   = pm + 9 * B_ * NP1;

        zero_kernel<<<(B_ * NP1 + 255) / 256, 256, 0, stream>>>(v, B_ * NP1);
        norms_kernel<<<(B_ * 2048) / 4, 256, 0, stream>>>(tf, df, inv1, inv2);
        gemm_s_kernel<false><<<1024, 256, 0, stream>>>(tf, df, tl, dl, inv1, inv2, eps, S);
        fill_edges_kernel<false><<<(B_ * (NP1 + M_) + 255) / 256, 256, 0, stream>>>(S, alpha, eps);

        for (int it = 0; it < NUM_SINK; ++it) {
            row_pass_kernel<<<rowblocks, 256, 0, stream>>>(S, v, u);
            col_pass1_kernel<<<dim3(5, 9, 16), 256, 0, stream>>>(S, u, pm, ps);
            col_pass2_kernel<<<dim3(5, 16), 256, 0, stream>>>(pm, ps, v);
        }
        row_final_kernel<<<rowblocks, 256, 0, stream>>>(S, v);
    }
}

// Round 5
// 262.625 us; speedup vs baseline: 3.5082x; 3.5082x over previous
//
#include <hip/hip_runtime.h>
#include <math.h>

#define B_ 16
#define M_ 1024
#define N_ 1024
#define D_ 512
#define MP1 1025
#define NP1 1025
#define NUM_SINK 8
#define BK 64
#define SH_STRIDE 1032   // fp16 row stride (elements), 16B-aligned rows
#define VSTR 1028        // v stride (floats), 16B-aligned
#define NCHUNK 65        // 64 chunks of 16 rows + 1 chunk (row 1024)
// log(1/2048), log(1/2)
#define LOG_NORM (-7.6246189861593985f)
#define LOG_HALF (-0.6931471805599453f)

typedef __attribute__((ext_vector_type(8))) short bf16x8;
typedef __attribute__((ext_vector_type(4))) float f32x4;
typedef __attribute__((ext_vector_type(8))) _Float16 h16x8;

__device__ inline short f2bf(float x) {
    unsigned u = __builtin_bit_cast(unsigned, x);
    u = (u + 0x7FFFu + ((u >> 16) & 1u)) >> 16;
    return (short)u;
}

// ---------------- norms: one wave per feature row ----------------
__global__ __launch_bounds__(256) void norms_kernel(
    const float* __restrict__ tf, const float* __restrict__ df,
    float* __restrict__ inv1, float* __restrict__ inv2)
{
    int w = (blockIdx.x * 256 + threadIdx.x) >> 6;
    int lane = threadIdx.x & 63;
    if (w >= B_ * 2048) return;
    int b = w >> 11;
    int rr = w & 2047;
    const float* src;
    float* dst;
    if (rr < M_) { src = tf + ((size_t)b * M_ + rr) * D_;        dst = inv1 + b * M_ + rr; }
    else         { src = df + ((size_t)b * N_ + (rr - M_)) * D_; dst = inv2 + b * N_ + (rr - M_); }
    float4 x = *(const float4*)(src + lane * 4);
    float4 y = *(const float4*)(src + 256 + lane * 4);
    float ss = x.x*x.x + x.y*x.y + x.z*x.z + x.w*x.w
             + y.x*y.x + y.y*y.y + y.z*y.z + y.w*y.w;
    #pragma unroll
    for (int o = 32; o; o >>= 1) ss += __shfl_xor(ss, o);
    if (lane == 0) *dst = 1.0f / sqrtf(ss);
}

// ---------------- MFMA GEMM + epilogue: S = (cos*mask - 1)/lambda ----------------
template<bool HALF>
__global__ __launch_bounds__(256) void gemm_s_kernel(
    const float* __restrict__ A, const float* __restrict__ Bm,
    const float* __restrict__ tl, const float* __restrict__ dl,
    const float* __restrict__ inv1, const float* __restrict__ inv2,
    const float* __restrict__ eps_p, void* __restrict__ Sout)
{
    __shared__ __align__(16) unsigned short As[128 * BK];
    __shared__ __align__(16) unsigned short Bs[128 * BK];

    int flat = blockIdx.x;
    int swz = (flat & 7) * 128 + (flat >> 3);
    int jb = swz & 7, ib = (swz >> 3) & 7;
    int b  = swz >> 6;
    int i0 = ib * 128;
    int j0 = jb * 128;

    const float* Ab = A  + (size_t)b * M_ * D_;
    const float* Bb = Bm + (size_t)b * N_ * D_;

    int tid  = threadIdx.x;
    int lane = tid & 63;
    int w    = tid >> 6;
    int wm   = w >> 1, wn = w & 1;

    int seg   = tid & 7;
    int rbase = tid >> 3;

    f32x4 acc[4][4] = {};

    for (int k0 = 0; k0 < D_; k0 += BK) {
        #pragma unroll
        for (int rr = 0; rr < 4; ++rr) {
            int r = rbase + rr * 32;
            int colx = (seg * 16) ^ ((r & 7) << 4);
            {
                const float* pa = Ab + (size_t)(i0 + r) * D_ + k0 + seg * 8;
                float4 a0 = *(const float4*)pa;
                float4 a1 = *(const float4*)(pa + 4);
                bf16x8 hv;
                hv[0] = f2bf(a0.x); hv[1] = f2bf(a0.y); hv[2] = f2bf(a0.z); hv[3] = f2bf(a0.w);
                hv[4] = f2bf(a1.x); hv[5] = f2bf(a1.y); hv[6] = f2bf(a1.z); hv[7] = f2bf(a1.w);
                *(bf16x8*)((char*)As + r * 128 + colx) = hv;
            }
            {
                const float* pb = Bb + (size_t)(j0 + r) * D_ + k0 + seg * 8;
                float4 b0 = *(const float4*)pb;
                float4 b1 = *(const float4*)(pb + 4);
                bf16x8 hv;
                hv[0] = f2bf(b0.x); hv[1] = f2bf(b0.y); hv[2] = f2bf(b0.z); hv[3] = f2bf(b0.w);
                hv[4] = f2bf(b1.x); hv[5] = f2bf(b1.y); hv[6] = f2bf(b1.z); hv[7] = f2bf(b1.w);
                *(bf16x8*)((char*)Bs + r * 128 + colx) = hv;
            }
        }
        __syncthreads();

        #pragma unroll
        for (int ks = 0; ks < 2; ++ks) {
            int kb = ks * 64 + ((lane >> 4) << 4);
            bf16x8 af[4], bfr[4];
            #pragma unroll
            for (int m = 0; m < 4; ++m) {
                int ra = wm * 64 + m * 16 + (lane & 15);
                af[m] = *(const bf16x8*)((const char*)As + ra * 128 + (kb ^ ((ra & 7) << 4)));
                int rb = wn * 64 + m * 16 + (lane & 15);
                bfr[m] = *(const bf16x8*)((const char*)Bs + rb * 128 + (kb ^ ((rb & 7) << 4)));
            }
            #pragma unroll
            for (int m = 0; m < 4; ++m)
                #pragma unroll
                for (int n = 0; n < 4; ++n)
                    acc[m][n] = __builtin_amdgcn_mfma_f32_16x16x32_bf16(af[m], bfr[n], acc[m][n], 0, 0, 0);
        }
        __syncthreads();
    }

    float lam = expf(eps_p[0]) + 0.03f;
    float inv_lam = 1.0f / lam;
    int crow0 = i0 + wm * 64;
    int ccol0 = j0 + wn * 64;
    int rlane = lane >> 4;
    int clane = lane & 15;

    float invb_[4], dlx_[4], dly_[4];
    #pragma unroll
    for (int n = 0; n < 4; ++n) {
        int j = ccol0 + n * 16 + clane;
        invb_[n] = inv2[b * N_ + j];
        dlx_[n]  = dl[((size_t)b * N_ + j) * 2 + 0];
        dly_[n]  = dl[((size_t)b * N_ + j) * 2 + 1];
    }
    #pragma unroll
    for (int m = 0; m < 4; ++m) {
        #pragma unroll
        for (int reg = 0; reg < 4; ++reg) {
            int i = crow0 + m * 16 + rlane * 4 + reg;
            float inva = inv1[b * M_ + i];
            float tlx  = tl[((size_t)b * M_ + i) * 2 + 0];
            float tly  = tl[((size_t)b * M_ + i) * 2 + 1];
            #pragma unroll
            for (int n = 0; n < 4; ++n) {
                float cosv = acc[m][n][reg] * inva * invb_[n];
                float dx = tlx - dlx_[n];
                float dy = tly - dly_[n];
                float msk = (sqrtf(dx * dx + dy * dy) <= 0.3f) ? 1.0f : 0.0f;
                float val = (cosv * msk - 1.0f) * inv_lam;
                int col = ccol0 + n * 16 + clane;
                if (HALF) {
                    _Float16* Srow = (_Float16*)Sout + ((size_t)b * MP1 + i) * SH_STRIDE;
                    Srow[col] = (_Float16)val;
                } else {
                    float* Srow = (float*)Sout + ((size_t)b * MP1 + i) * NP1;
                    Srow[col] = val;
                }
            }
        }
    }
}

// ---------------- fill dustbin row/col ----------------
template<bool HALF>
__global__ __launch_bounds__(256) void fill_edges_kernel(
    void* __restrict__ Sout, const float* __restrict__ alpha_p, const float* __restrict__ eps_p)
{
    int t = blockIdx.x * 256 + threadIdx.x;
    if (t >= B_ * (NP1 + M_)) return;
    int b = t / (NP1 + M_), r = t % (NP1 + M_);
    float lam = expf(eps_p[0]) + 0.03f;
    float s = (alpha_p[0] - 1.0f) / lam;
    size_t stride = HALF ? SH_STRIDE : NP1;
    size_t idx;
    if (r < NP1) idx = ((size_t)b * MP1 + M_) * stride + r;
    else         idx = ((size_t)b * MP1 + (r - NP1)) * stride + N_;
    if (HALF) ((_Float16*)Sout)[idx] = (_Float16)s;
    else      ((float*)Sout)[idx] = s;
}

// ================= fp16 path: fused row-update + column partials =================
// One Sinkhorn iteration's S-read happens HERE, once. Max-free LSE.
// Column partials include exp(v_old); col_pass2_f compensates with +v_old.
__global__ __launch_bounds__(256) void fused_rowcol_h(
    const _Float16* __restrict__ Sh, const float* __restrict__ v,
    float* __restrict__ ps)
{
    int b = blockIdx.y;
    int chunk = blockIdx.x;      // 0..64
    int tid = threadIdx.x;
    int lane = tid & 63;
    int w = tid >> 6;

    __shared__ float red[4][17][64];   // [wave][e][lane]

    const float* vb = v + (size_t)b * VSTR;
    float vreg[16];
    {
        float4 v0 = *(const float4*)(vb + lane * 8);
        float4 v1 = *(const float4*)(vb + lane * 8 + 4);
        float4 v2 = *(const float4*)(vb + 512 + lane * 8);
        float4 v3 = *(const float4*)(vb + 512 + lane * 8 + 4);
        vreg[0]=v0.x; vreg[1]=v0.y; vreg[2]=v0.z; vreg[3]=v0.w;
        vreg[4]=v1.x; vreg[5]=v1.y; vreg[6]=v1.z; vreg[7]=v1.w;
        vreg[8]=v2.x; vreg[9]=v2.y; vreg[10]=v2.z; vreg[11]=v2.w;
        vreg[12]=v3.x; vreg[13]=v3.y; vreg[14]=v3.z; vreg[15]=v3.w;
    }
    float v1024 = vb[1024];

    float creg[16] = {};
    float creg16 = 0.f;

    #pragma unroll
    for (int rr = 0; rr < 4; ++rr) {
        int i = chunk * 16 + w * 4 + rr;
        if (i < MP1) {
            const _Float16* row = Sh + ((size_t)b * MP1 + i) * SH_STRIDE;
            h16x8 h0 = *(const h16x8*)(row + lane * 8);
            h16x8 h1 = *(const h16x8*)(row + 512 + lane * 8);
            float et[16];
            float rs = 0.f;
            #pragma unroll
            for (int e = 0; e < 8; ++e) { et[e] = expf((float)h0[e] + vreg[e]); rs += et[e]; }
            #pragma unroll
            for (int e = 0; e < 8; ++e) { et[8 + e] = expf((float)h1[e] + vreg[8 + e]); rs += et[8 + e]; }
            float et16 = 0.f;
            if (lane == 0) { et16 = expf((float)row[1024] + v1024); rs += et16; }
            #pragma unroll
            for (int o = 32; o; o >>= 1) rs += __shfl_xor(rs, o);
            float A = (i == M_) ? 0.5f : (1.0f / 2048.0f);   // exp(log_a)
            float scale = A / rs;                             // exp(u_i)
            #pragma unroll
            for (int e = 0; e < 16; ++e) creg[e] += et[e] * scale;
            creg16 += et16 * scale;                           // nonzero only on lane 0
        }
    }

    #pragma unroll
    for (int e = 0; e < 16; ++e) red[w][e][lane] = creg[e];
    red[w][16][lane] = creg16;
    __syncthreads();

    float* out = ps + ((size_t)chunk * B_ + b) * NP1;
    for (int j = tid; j < 1024; j += 256) {
        int lane_j = (j < 512) ? (j >> 3) : ((j - 512) >> 3);
        int e_j    = (j < 512) ? (j & 7) : (8 + (j & 7));
        float s = red[0][e_j][lane_j] + red[1][e_j][lane_j]
                + red[2][e_j][lane_j] + red[3][e_j][lane_j];
        out[j] = s;
    }
    if (tid == 0) {
        float s = red[0][16][0] + red[1][16][0] + red[2][16][0] + red[3][16][0];
        out[1024] = s;
    }
}

// combine chunk partials -> v. colsum = sum_i exp(s+u+v_old), so
// v_new = v_old + lb - log(colsum)   (the +v_old was the round-4 bug)
__global__ __launch_bounds__(256) void col_pass2_f(
    const float* __restrict__ ps, float* __restrict__ v)
{
    int j = blockIdx.x * 256 + threadIdx.x;
    int b = blockIdx.y;
    if (j >= NP1) return;
    float s = 0.f;
    for (int c = 0; c < NCHUNK; ++c) s += ps[((size_t)c * B_ + b) * NP1 + j];
    float lb = (j == N_) ? LOG_HALF : LOG_NORM;
    size_t idx = (size_t)b * VSTR + j;
    float vold = v[idx];
    v[idx] = vold + lb - logf(s);
}

// fused final row pass + finalize: reads fp16 S, writes fp32 out (max-free)
__global__ __launch_bounds__(256) void row_final_h(
    const _Float16* __restrict__ Sh, const float* __restrict__ v, float* __restrict__ out)
{
    int w = (blockIdx.x * 256 + threadIdx.x) >> 6;
    int lane = threadIdx.x & 63;
    if (w >= B_ * MP1) return;
    int b = w / MP1, i = w % MP1;
    const _Float16* row = Sh + ((size_t)b * MP1 + i) * SH_STRIDE;
    float* orow = out + ((size_t)b * MP1 + i) * NP1;
    const float* vb = v + (size_t)b * VSTR;
    float et[17];
    float sm = 0.f;
    #pragma unroll
    for (int q = 0; q < 17; ++q) {
        int j = lane + q * 64;
        float e = 0.f;
        if (j < NP1) e = expf((float)row[j] + vb[j]);
        et[q] = e;
        sm += e;
    }
    #pragma unroll
    for (int o = 32; o; o >>= 1) sm += __shfl_xor(sm, o);
    float A = (i == M_) ? 0.5f : (1.0f / 2048.0f);
    float scale = (A / sm) * 2048.0f;
    #pragma unroll
    for (int q = 0; q < 17; ++q) {
        int j = lane + q * 64;
        if (j < NP1) orow[j] = et[q] * scale;
    }
}

// ================= fp32 fallback kernels (S in d_out) =================

__global__ __launch_bounds__(256) void row_pass_kernel(
    const float* __restrict__ S, const float* __restrict__ v, float* __restrict__ u)
{
    int w = (blockIdx.x * 256 + threadIdx.x) >> 6;
    int lane = threadIdx.x & 63;
    if (w >= B_ * MP1) return;
    int b = w / MP1, i = w % MP1;
    const float* row = S + ((size_t)b * MP1 + i) * NP1;
    const float* vb = v + b * NP1;
    float sm = 0.f;
    #pragma unroll
    for (int q = 0; q < 17; ++q) {
        int j = lane + q * 64;
        if (j < NP1) sm += expf(row[j] + vb[j]);
    }
    #pragma unroll
    for (int o = 32; o; o >>= 1) sm += __shfl_xor(sm, o);
    if (lane == 0) {
        float la = (i == M_) ? LOG_HALF : LOG_NORM;
        u[b * MP1 + i] = la - logf(sm);
    }
}

__global__ __launch_bounds__(256) void col_pass1_kernel(
    const float* __restrict__ S, const float* __restrict__ u,
    float* __restrict__ pm, float* __restrict__ ps)
{
    int j = blockIdx.x * 256 + threadIdx.x;
    int b = blockIdx.z;
    int i0 = blockIdx.y * 128;
    int i1 = min(i0 + 128, MP1);
    if (j >= NP1) return;
    const float* p  = S + ((size_t)b * MP1 + i0) * NP1 + j;
    const float* ub = u + b * MP1;
    float sm = 0.f;
    for (int i = i0; i < i1; ++i) {
        sm += expf(*p + ub[i]);
        p += NP1;
    }
    int idx = (blockIdx.y * B_ + b) * NP1 + j;
    pm[idx] = 0.f;
    ps[idx] = sm;
}

__global__ __launch_bounds__(256) void col_pass2_kernel(
    const float* __restrict__ pm, const float* __restrict__ ps, float* __restrict__ v)
{
    int j = blockIdx.x * 256 + threadIdx.x;
    int b = blockIdx.y;
    if (j >= NP1) return;
    float Ssum = 0.f;
    #pragma unroll
    for (int c = 0; c < 9; ++c) Ssum += ps[(c * B_ + b) * NP1 + j];
    float lb = (j == N_) ? LOG_HALF : LOG_NORM;
    v[b * NP1 + j] = lb - logf(Ssum);
}

__global__ __launch_bounds__(256) void row_final_kernel(
    float* __restrict__ S, const float* __restrict__ v)
{
    int w = (blockIdx.x * 256 + threadIdx.x) >> 6;
    int lane = threadIdx.x & 63;
    if (w >= B_ * MP1) return;
    int b = w / MP1, i = w % MP1;
    float* row = S + ((size_t)b * MP1 + i) * NP1;
    const float* vb = v + b * NP1;
    float et[17];
    float sm = 0.f;
    #pragma unroll
    for (int q = 0; q < 17; ++q) {
        int j = lane + q * 64;
        float e = 0.f;
        if (j < NP1) e = expf(row[j] + vb[j]);
        et[q] = e;
        sm += e;
    }
    #pragma unroll
    for (int o = 32; o; o >>= 1) sm += __shfl_xor(sm, o);
    float A = (i == M_) ? 0.5f : (1.0f / 2048.0f);
    float scale = (A / sm) * 2048.0f;
    #pragma unroll
    for (int q = 0; q < 17; ++q) {
        int j = lane + q * 64;
        if (j < NP1) row[j] = et[q] * scale;
    }
}

// ---------------- zero helper ----------------
__global__ __launch_bounds__(256) void zero_kernel(float* __restrict__ p, int n)
{
    int i = blockIdx.x * 256 + threadIdx.x;
    if (i < n) p[i] = 0.f;
}

extern "C" void kernel_launch(void* const* d_in, const int* in_sizes, int n_in,
                              void* d_out, int out_size, void* d_ws, size_t ws_size,
                              hipStream_t stream)
{
    const float* tf    = (const float*)d_in[0];
    const float* df    = (const float*)d_in[1];
    const float* tl    = (const float*)d_in[2];
    const float* dl    = (const float*)d_in[3];
    const float* alpha = (const float*)d_in[4];
    const float* eps   = (const float*)d_in[5];
    float* out = (float*)d_out;

    const size_t sh_elems = (size_t)B_ * MP1 * SH_STRIDE;
    const size_t sh_bytes = sh_elems * sizeof(_Float16);
    const size_t small_floats = (size_t)B_ * M_ * 2 + (size_t)B_ * VSTR;  // inv1, inv2, v
    const bool use_half = ws_size >= sh_bytes + small_floats * 4 + 512;

    int rowblocks = (B_ * MP1 + 3) / 4;

    if (use_half) {
        _Float16* Sh = (_Float16*)d_ws;
        float* fbase = (float*)((char*)d_ws + ((sh_bytes + 255) & ~(size_t)255));
        float* inv1 = fbase;
        float* inv2 = inv1 + B_ * M_;
        float* v    = inv2 + B_ * N_;
        float* ps   = out;   // chunk partials live in d_out until row_final overwrites it

        zero_kernel<<<(B_ * VSTR + 255) / 256, 256, 0, stream>>>(v, B_ * VSTR);
        norms_kernel<<<(B_ * 2048) / 4, 256, 0, stream>>>(tf, df, inv1, inv2);
        gemm_s_kernel<true><<<1024, 256, 0, stream>>>(tf, df, tl, dl, inv1, inv2, eps, Sh);
        fill_edges_kernel<true><<<(B_ * (NP1 + M_) + 255) / 256, 256, 0, stream>>>(Sh, alpha, eps);

        for (int it = 0; it < NUM_SINK; ++it) {
            fused_rowcol_h<<<dim3(NCHUNK, B_), 256, 0, stream>>>(Sh, v, ps);
            col_pass2_f<<<dim3(5, B_), 256, 0, stream>>>(ps, v);
        }
        row_final_h<<<rowblocks, 256, 0, stream>>>(Sh, v, out);
    } else {
        float* S = out;
        float* ws = (float*)d_ws;
        float* inv1 = ws;
        float* inv2 = inv1 + B_ * M_;
        float* u    = inv2 + B_ * N_;
        float* v    = u + B_ * MP1;
        float* pm   = v + B_ * NP1;
        float* ps   = pm + 9 * B_ * NP1;

        zero_kernel<<<(B_ * NP1 + 255) / 256, 256, 0, stream>>>(v, B_ * NP1);
        norms_kernel<<<(B_ * 2048) / 4, 256, 0, stream>>>(tf, df, inv1, inv2);
        gemm_s_kernel<false><<<1024, 256, 0, stream>>>(tf, df, tl, dl, inv1, inv2, eps, S);
        fill_edges_kernel<false><<<(B_ * (NP1 + M_) + 255) / 256, 256, 0, stream>>>(S, alpha, eps);

        for (int it = 0; it < NUM_SINK; ++it) {
            row_pass_kernel<<<rowblocks, 256, 0, stream>>>(S, v, u);
            col_pass1_kernel<<<dim3(5, 9, 16), 256, 0, stream>>>(S, u, pm, ps);
            col_pass2_kernel<<<dim3(5, 16), 256, 0, stream>>>(pm, ps, v);
        }
        row_final_kernel<<<rowblocks, 256, 0, stream>>>(S, v);
    }
}